// Round 1
// 152.862 us; speedup vs baseline: 1.0039x; 1.0039x over previous
//
#include <hip/hip_runtime.h>
#include <math.h>

#define NROWS 8192
#define HALF  4096
#define EMB   2048
#define DIM   256
#define INV_T 10.0f

typedef __bf16 bf16x8v __attribute__((ext_vector_type(8)));
typedef __bf16 bf16x4v __attribute__((ext_vector_type(4)));
typedef float  f32x4   __attribute__((ext_vector_type(4)));

__device__ __forceinline__ void gld_lds16(const void* g, void* l) {
    __builtin_amdgcn_global_load_lds((const __attribute__((address_space(1))) void*)g,
                                     (__attribute__((address_space(3))) void*)l,
                                     16, 0, 0);
}

// ---------- K0: W [2048][256] f32 -> Wt [256][2048] bf16, coalesced tile transpose ----------
__global__ __launch_bounds__(256) void wt_kernel(const float* __restrict__ W,
                                                 __bf16* __restrict__ Wt) {
    __shared__ __bf16 t[64][72];
    const int n0 = blockIdx.x * 64;
    const int k0 = blockIdx.y * 64;
    const int tid = threadIdx.x;
    const int c = tid & 63;
    const int rr = tid >> 6;
#pragma unroll
    for (int it = 0; it < 16; it++) {
        int k = it * 4 + rr;
        t[k][c] = (__bf16)W[(size_t)(k0 + k) * DIM + n0 + c];
    }
    __syncthreads();
#pragma unroll
    for (int it = 0; it < 16; it++) {
        int n = it * 4 + rr;
        Wt[(size_t)(n0 + n) * EMB + k0 + c] = t[c][n];
    }
}

// ---------- K1a: partial GEMM. Tile 64(M) x 256(N) x 512(Kchunk), BK=64, 8 iters ----------
// LDS rows are 64 B => naive frag reads would 8-way bank-conflict. Fix: XOR-swizzle
// the 16B k-granule within each row (inverse-permuted global SOURCE at stage time,
// since global_load_lds dest must stay linear; same XOR applied on the read side).
#define KSPLIT  4
#define KCHUNK  (EMB / KSPLIT)   // 512
#define K1_BK   64

__global__ __launch_bounds__(256) void gemm_part_kernel(
    const float* __restrict__ A,      // [8192][2048] f32
    const __bf16* __restrict__ Wt,    // [256][2048] bf16
    float* __restrict__ parts)        // [4][8192][256] f32
{
    __shared__ float  a_sh[4][64][16];     // 16 KB
    __shared__ __bf16 b_sh[2][DIM][32];    // 32 KB

    const int tid  = threadIdx.x;
    const int wave = tid >> 6, lane = tid & 63;
    const int quad = lane >> 4, l15 = lane & 15;
    const int rowBase = blockIdx.x * 64;
    const int kOff    = blockIdx.y * KCHUNK;
    const int waveCol = wave * 64;

    f32x4 acc[4][4];
    const f32x4 zero = {0.f, 0.f, 0.f, 0.f};
#pragma unroll
    for (int m = 0; m < 4; m++)
#pragma unroll
        for (int n = 0; n < 4; n++) acc[m][n] = zero;

    const int r16 = lane >> 2;
    const int b4  = (lane & 3);
    const int sw  = (r16 >> 1) & 3;   // stage-side swizzle (row = ...*16 + r16)
    const int sr  = (l15 >> 1) & 3;   // read-side swizzle  (row = ...*16 + l15)

    for (int k0 = 0; k0 < KCHUNK; k0 += K1_BK) {
        __syncthreads();
#pragma unroll
        for (int j = 0; j < 4; j++) {
            const float* src = A + (size_t)(rowBase + j * 16 + r16) * EMB
                                 + kOff + k0 + wave * 16 + (b4 ^ sw) * 4;
            float* dst = (float*)a_sh + ((wave * 64 + j * 16) * 16);
            gld_lds16(src, dst);
        }
#pragma unroll
        for (int h = 0; h < 2; h++)
#pragma unroll
            for (int j = 0; j < 4; j++) {
                int g = wave * 4 + j;
                const __bf16* src = Wt + (size_t)(g * 16 + r16) * EMB
                                       + kOff + k0 + h * 32 + (b4 ^ sw) * 8;
                __bf16* dst = (__bf16*)b_sh + ((h * DIM + g * 16) * 32);
                gld_lds16(src, dst);
            }
        __syncthreads();
#pragma unroll
        for (int h = 0; h < 2; h++) {
            bf16x8v af[4], bfv[4];
#pragma unroll
            for (int m = 0; m < 4; m++) {
                int c   = h * 2 + (quad >> 1);
                int g0  = ((quad & 1) * 2) ^ sr;   // granule of low 4 floats
                int g1  = g0 ^ 1;                  // granule of high 4 floats
                f32x4 v0 = *(const f32x4*)&a_sh[c][m * 16 + l15][g0 * 4];
                f32x4 v1 = *(const f32x4*)&a_sh[c][m * 16 + l15][g1 * 4];
#pragma unroll
                for (int i = 0; i < 4; i++) { af[m][i] = (__bf16)v0[i]; af[m][4 + i] = (__bf16)v1[i]; }
            }
#pragma unroll
            for (int n = 0; n < 4; n++)
                bfv[n] = *(const bf16x8v*)&b_sh[h][waveCol + n * 16 + l15][(quad ^ sr) * 8];
#pragma unroll
            for (int m = 0; m < 4; m++)
#pragma unroll
                for (int n = 0; n < 4; n++)
                    acc[m][n] = __builtin_amdgcn_mfma_f32_16x16x32_bf16(af[m], bfv[n], acc[m][n], 0, 0, 0);
        }
    }

    float* p = parts + (size_t)blockIdx.y * NROWS * DIM;
#pragma unroll
    for (int m = 0; m < 4; m++)
#pragma unroll
        for (int n = 0; n < 4; n++)
#pragma unroll
            for (int r = 0; r < 4; r++)
                p[(size_t)(rowBase + m * 16 + quad * 4 + r) * DIM + waveCol + n * 16 + l15] =
                    acc[m][n][r];
}

// ---------- K1b: sum partials + bias, L2-normalize, emit bf16 X ----------
__global__ __launch_bounds__(256) void norm_kernel(
    const float* __restrict__ parts,
    const float* __restrict__ bias,
    __bf16* __restrict__ outb)
{
    const int tid  = threadIdx.x;
    const int wave = tid >> 6, lane = tid & 63;
    const int row  = blockIdx.x * 4 + wave;

    float4 v = {0.f, 0.f, 0.f, 0.f};
#pragma unroll
    for (int kc = 0; kc < KSPLIT; kc++) {
        float4 pv = *(const float4*)(parts + (size_t)kc * NROWS * DIM + (size_t)row * DIM + lane * 4);
        v.x += pv.x; v.y += pv.y; v.z += pv.z; v.w += pv.w;
    }
    float4 bv = ((const float4*)bias)[lane];
    v.x += bv.x; v.y += bv.y; v.z += bv.z; v.w += bv.w;

    float ss = v.x * v.x + v.y * v.y + v.z * v.z + v.w * v.w;
#pragma unroll
    for (int off = 1; off < 64; off <<= 1) ss += __shfl_xor(ss, off, 64);
    float inv = 1.f / fmaxf(sqrtf(ss), 1e-12f);

    bf16x4v o;
    o[0] = (__bf16)(v.x * inv); o[1] = (__bf16)(v.y * inv);
    o[2] = (__bf16)(v.z * inv); o[3] = (__bf16)(v.w * inv);
    *(bf16x4v*)(outb + (size_t)row * DIM + lane * 4) = o;
}

// ---------- K1 fallback (small ws): single-kernel GEMM+norm ----------
__global__ __launch_bounds__(256) void gemm_norm_kernel(
    const float* __restrict__ A, const __bf16* __restrict__ Wt,
    const float* __restrict__ bias, __bf16* __restrict__ outb)
{
    __shared__ __bf16 a_shF[32][32];
    __shared__ __bf16 b_shF[DIM][32];
    __shared__ float norm2[32];

    const int tid  = threadIdx.x;
    const int wave = tid >> 6, lane = tid & 63;
    const int quad = lane >> 4, l15 = lane & 15;
    const int rowBase = blockIdx.x * 32;
    const int waveRow = (wave >> 1) * 16;
    const int waveCol = (wave & 1) * 128;

    f32x4 acc[8];
    const f32x4 zero = {0.f, 0.f, 0.f, 0.f};
#pragma unroll
    for (int s = 0; s < 8; s++) acc[s] = zero;

    const int ar = tid >> 3;
    const int ac = (tid & 7) * 4;
    const float* aptr = A + (size_t)(rowBase + ar) * EMB + ac;
    float4 a_cur = *(const float4*)aptr;

    for (int k0 = 0; k0 < EMB; k0 += 32) {
        __syncthreads();
        bf16x4v av;
        av[0] = (__bf16)a_cur.x; av[1] = (__bf16)a_cur.y;
        av[2] = (__bf16)a_cur.z; av[3] = (__bf16)a_cur.w;
        *(bf16x4v*)&a_shF[ar][ac] = av;
#pragma unroll
        for (int j = 0; j < 4; j++) {
            int seg = wave * 4 + j;
            int n = seg * 16 + (lane >> 2);
            int kloc = (lane & 3) * 8;
            gld_lds16(Wt + (size_t)n * EMB + k0 + kloc, (__bf16*)b_shF + seg * 512);
        }
        if (k0 + 32 < EMB) a_cur = *(const float4*)(aptr + k0 + 32);
        __syncthreads();
        bf16x8v af = *(const bf16x8v*)&a_shF[waveRow + l15][quad * 8];
#pragma unroll
        for (int s = 0; s < 8; s++) {
            bf16x8v bfv = *(const bf16x8v*)&b_shF[waveCol + s * 16 + l15][quad * 8];
            acc[s] = __builtin_amdgcn_mfma_f32_16x16x32_bf16(af, bfv, acc[s], 0, 0, 0);
        }
    }

    __syncthreads();
    if (tid < 32) norm2[tid] = 0.f;
    __syncthreads();

    float bv[8];
#pragma unroll
    for (int s = 0; s < 8; s++) bv[s] = bias[waveCol + s * 16 + l15];

    float vals[8][4];
    float ss[4] = {0.f, 0.f, 0.f, 0.f};
#pragma unroll
    for (int s = 0; s < 8; s++)
#pragma unroll
        for (int r = 0; r < 4; r++) {
            float v = acc[s][r] + bv[s];
            vals[s][r] = v;
            ss[r] += v * v;
        }
#pragma unroll
    for (int off = 1; off < 16; off <<= 1)
#pragma unroll
        for (int r = 0; r < 4; r++) ss[r] += __shfl_xor(ss[r], off, 64);
    if (l15 == 0)
#pragma unroll
        for (int r = 0; r < 4; r++) atomicAdd(&norm2[waveRow + quad * 4 + r], ss[r]);
    __syncthreads();

    float inv[4];
#pragma unroll
    for (int r = 0; r < 4; r++)
        inv[r] = 1.f / fmaxf(sqrtf(norm2[waveRow + quad * 4 + r]), 1e-12f);

    __bf16* c_sh = &b_shF[0][0];
#pragma unroll
    for (int s = 0; s < 8; s++)
#pragma unroll
        for (int r = 0; r < 4; r++)
            c_sh[(waveRow + quad * 4 + r) * DIM + waveCol + s * 16 + l15] =
                (__bf16)(vals[s][r] * inv[r]);
    __syncthreads();

    const int4* src = (const int4*)c_sh;
    int4* dst = (int4*)(outb + (size_t)rowBase * DIM);
#pragma unroll
    for (int it = 0; it < 4; it++) dst[it * 256 + tid] = src[it * 256 + tid];
}

// ---------- K2: sim = X@X^T. BK=64 streaming (32 KB LDS -> 3+ blocks/CU),
//              XOR-swizzled staging (kills the 8-way ds_read_b128 bank conflict),
//              shuffle-free unique-writer LDS epilogue, upper-tri grid ----------
#define TILE 128
#define NTILE (NROWS / TILE)              // 64
#define NBLK  (NTILE * (NTILE + 1) / 2)   // 2080

__global__ __launch_bounds__(256, 3) void sim_kernel(
    const __bf16* __restrict__ X,
    float* __restrict__ total,
    float* __restrict__ posv)
{
    // 32 KB shared: staging [2 ops][2 kchunks][128 rows][32 k] bf16,
    // later reused as reduce scratch rs[128][2][16] f32 + cs[128][2][4] f32.
    __shared__ __align__(16) char smem[32768];
    __bf16* a_base = (__bf16*)smem;            // [2][128][32]
    __bf16* b_base = (__bf16*)(smem + 16384);  // [2][128][32]
    float*  rs     = (float*)smem;             // [128][2][16] = 16 KB
    float*  cs     = (float*)(smem + 16384);   // [128][2][4]  = 4 KB

    // linear -> upper-triangle (bx, by); row-major so consecutive blocks share bx
    const int t = blockIdx.x;
    int bx = (int)((129.0 - sqrt(16641.0 - 8.0 * (double)t)) * 0.5);
    while (64 * (bx + 1) - ((bx + 1) * bx) / 2 <= t) bx++;
    while (64 * bx - (bx * (bx - 1)) / 2 > t) bx--;
    const int by = bx + (t - (64 * bx - (bx * (bx - 1)) / 2));
    const bool diag = (bx == by);

    const int tid  = threadIdx.x;
    const int wave = tid >> 6, lane = tid & 63;
    const int quad = lane >> 4, l15 = lane & 15;
    const int rowBase = bx * TILE;
    const int colBase = by * TILE;
    const int waveRow = (wave >> 1) * 64;
    const int waveCol = (wave & 1) * 64;

    f32x4 acc[4][4];
    const f32x4 zero = {0.f, 0.f, 0.f, 0.f};
#pragma unroll
    for (int m = 0; m < 4; m++)
#pragma unroll
        for (int n = 0; n < 4; n++) acc[m][n] = zero;

    const int r16 = lane >> 2;
    const int b4  = lane & 3;
    const int sw  = (r16 >> 1) & 3;   // stage-side swizzle
    const int sr  = (l15 >> 1) & 3;   // read-side swizzle

    for (int k0 = 0; k0 < DIM; k0 += 64) {
        __syncthreads();
        // stage 64 k-cols of A-rows and B-rows: per wave 4+4 issues of 1 KB.
        // Source k-granule is XOR-permuted per row so linear LDS dest ends up swizzled.
#pragma unroll
        for (int c = 0; c < 2; c++) {
#pragma unroll
            for (int j = 0; j < 2; j++) {
                int rg = wave * 2 + j;   // row-group 0..7
                const __bf16* asrc = X + (size_t)(rowBase + rg * 16 + r16) * DIM + k0 + c * 32 + (b4 ^ sw) * 8;
                const __bf16* bsrc = X + (size_t)(colBase + rg * 16 + r16) * DIM + k0 + c * 32 + (b4 ^ sw) * 8;
                gld_lds16(asrc, a_base + (c * TILE + rg * 16) * 32);
                gld_lds16(bsrc, b_base + (c * TILE + rg * 16) * 32);
            }
        }
        __syncthreads();
#pragma unroll
        for (int ks = 0; ks < 2; ks++) {
            bf16x8v af[4], bfv[4];
#pragma unroll
            for (int m = 0; m < 4; m++)
                af[m] = *(const bf16x8v*)(a_base + (ks * TILE + waveRow + m * 16 + l15) * 32 + (quad ^ sr) * 8);
#pragma unroll
            for (int n = 0; n < 4; n++)
                bfv[n] = *(const bf16x8v*)(b_base + (ks * TILE + waveCol + n * 16 + l15) * 32 + (quad ^ sr) * 8);
#pragma unroll
            for (int m = 0; m < 4; m++)
#pragma unroll
                for (int n = 0; n < 4; n++)
                    acc[m][n] = __builtin_amdgcn_mfma_f32_16x16x32_bf16(af[m], bfv[n], acc[m][n], 0, 0, 0);
        }
    }

    // ---- epilogue: per-lane partial sums (no shuffles) ----
    float es[4][4];     // row partial: sum over n, per (m,r)
    float ecol[4];      // col partial: sum over (m,r), per n
#pragma unroll
    for (int n = 0; n < 4; n++) ecol[n] = 0.f;
#pragma unroll
    for (int m = 0; m < 4; m++) {
#pragma unroll
        for (int r = 0; r < 4; r++) {
            int grow = rowBase + waveRow + m * 16 + quad * 4 + r;
            float e_acc = 0.f;
#pragma unroll
            for (int n = 0; n < 4; n++) {
                int gcol = colBase + waveCol + n * 16 + l15;
                float s = acc[m][n][r];
                if (gcol - grow == HALF) { posv[grow] = s; posv[gcol] = s; }
                float e = (gcol == grow) ? 0.f : __expf(s * INV_T);
                e_acc += e;
                ecol[n] += e;
            }
            es[m][r] = e_acc;
        }
    }

    __syncthreads();   // staging LDS is dead; reuse as reduce scratch
    // unique-writer stores: rs[row][waveCol-half][l15], cs[col][waveRow-half][quad]
    const int wc = wave & 1;        // waveCol half
    const int wr = wave >> 1;       // waveRow half
#pragma unroll
    for (int m = 0; m < 4; m++)
#pragma unroll
        for (int r = 0; r < 4; r++) {
            int lrow = waveRow + m * 16 + quad * 4 + r;
            rs[(lrow * 2 + wc) * 16 + l15] = es[m][r];
        }
    if (!diag) {
#pragma unroll
        for (int n = 0; n < 4; n++) {
            int lcol = waveCol + n * 16 + l15;
            cs[(lcol * 2 + wr) * 4 + quad] = ecol[n];
        }
    }
    __syncthreads();

    if (tid < TILE) {
        float rsum = 0.f;
#pragma unroll
        for (int i = 0; i < 32; i++) rsum += rs[tid * 32 + i];
        atomicAdd(&total[rowBase + tid], rsum);
        if (!diag) {
            float csum = 0.f;
#pragma unroll
            for (int i = 0; i < 8; i++) csum += cs[tid * 8 + i];
            atomicAdd(&total[colBase + tid], csum);
        }
    }
}

// ---------- K3: loss ----------
__global__ __launch_bounds__(256) void loss_kernel(
    const float* __restrict__ total, const float* __restrict__ posv,
    float* __restrict__ out)
{
    __shared__ float red[4];
    const int tid = threadIdx.x;
    const int i = blockIdx.x * 256 + tid;
    float s = posv[i] * INV_T - __logf(total[i]);
#pragma unroll
    for (int off = 1; off < 64; off <<= 1) s += __shfl_xor(s, off, 64);
    if ((tid & 63) == 0) red[tid >> 6] = s;
    __syncthreads();
    if (tid == 0) {
        float v = red[0] + red[1] + red[2] + red[3];
        atomicAdd(out, -v / (float)NROWS);
    }
}

extern "C" void kernel_launch(void* const* d_in, const int* in_sizes, int n_in,
                              void* d_out, int out_size, void* d_ws, size_t ws_size,
                              hipStream_t stream) {
    const float* emb  = (const float*)d_in[0];
    const float* W    = (const float*)d_in[1];
    const float* bias = (const float*)d_in[2];
    float* out = (float*)d_out;

    char* ws = (char*)d_ws;
    const size_t partsBytes = (size_t)KSPLIT * NROWS * DIM * sizeof(float);   // 32 MB
    const bool big = ws_size >= partsBytes + (6u << 20);

    __bf16* outb; __bf16* Wt; float* total; float* posv; float* parts = nullptr;
    if (big) {
        parts = (float*)ws;
        outb  = (__bf16*)(ws + partsBytes);
        Wt    = (__bf16*)(ws + partsBytes + (4u << 20));
        total = (float*)(ws + partsBytes + (5u << 20));
        posv  = (float*)(ws + partsBytes + (5u << 20) + (32u << 10));
    } else {
        outb  = (__bf16*)ws;
        Wt    = (__bf16*)(ws + (4u << 20));
        total = (float*)(ws + (5u << 20));
        posv  = (float*)(ws + (5u << 20) + (32u << 10));
    }

    hipMemsetAsync(total, 0, NROWS * sizeof(float), stream);
    hipMemsetAsync(out, 0, sizeof(float), stream);

    wt_kernel<<<dim3(DIM / 64, EMB / 64), 256, 0, stream>>>(W, Wt);
    if (big) {
        gemm_part_kernel<<<dim3(NROWS / 64, KSPLIT), 256, 0, stream>>>(emb, Wt, parts);
        norm_kernel<<<dim3(NROWS / 4), 256, 0, stream>>>(parts, bias, outb);
    } else {
        gemm_norm_kernel<<<dim3(NROWS / 32), 256, 0, stream>>>(emb, Wt, bias, outb);
    }
    sim_kernel<<<dim3(NBLK), 256, 0, stream>>>(outb, total, posv);
    loss_kernel<<<dim3(NROWS / 256), 256, 0, stream>>>(total, posv, out);
}

// Round 2
// 150.940 us; speedup vs baseline: 1.0167x; 1.0127x over previous
//
#include <hip/hip_runtime.h>
#include <math.h>

#define NROWS 8192
#define HALF  4096
#define EMB   2048
#define DIM   256
#define INV_T 10.0f

typedef __bf16 bf16x8v __attribute__((ext_vector_type(8)));
typedef __bf16 bf16x4v __attribute__((ext_vector_type(4)));
typedef float  f32x4   __attribute__((ext_vector_type(4)));

__device__ __forceinline__ void gld_lds16(const void* g, void* l) {
    __builtin_amdgcn_global_load_lds((const __attribute__((address_space(1))) void*)g,
                                     (__attribute__((address_space(3))) void*)l,
                                     16, 0, 0);
}

// ---------- K0: W [2048][256] f32 -> Wt [256][2048] bf16, coalesced tile transpose ----------
__global__ __launch_bounds__(256) void wt_kernel(const float* __restrict__ W,
                                                 __bf16* __restrict__ Wt) {
    __shared__ __bf16 t[64][72];
    const int n0 = blockIdx.x * 64;
    const int k0 = blockIdx.y * 64;
    const int tid = threadIdx.x;
    const int c = tid & 63;
    const int rr = tid >> 6;
#pragma unroll
    for (int it = 0; it < 16; it++) {
        int k = it * 4 + rr;
        t[k][c] = (__bf16)W[(size_t)(k0 + k) * DIM + n0 + c];
    }
    __syncthreads();
#pragma unroll
    for (int it = 0; it < 16; it++) {
        int n = it * 4 + rr;
        Wt[(size_t)(n0 + n) * EMB + k0 + c] = t[c][n];
    }
}

// ---------- K1: fused GEMM + bias + L2-normalize, emit bf16 X ----------
// 256 blocks x 32 rows x 256 cols, full K=2048, BK=64 (32 iters).
// Reg-staged double-buffered LDS (no global_load_lds => no forced vmcnt(0) drain
// at barriers; compiler emits counted vmcnt). A prefetched 2 iters ahead (HBM
// latency ~900cy > 1 iter), B 1 iter ahead (L2-resident Wt, ~300cy).
// Granule-XOR swizzle (slot = g ^ (row&7)) on both ds_write and ds_read sides.
#define FR   32              // rows per block
#define FBK  64              // k per iteration
#define FNIT (EMB / FBK)     // 32

__global__ __launch_bounds__(256) void gemm_norm_fused(
    const float* __restrict__ A,      // [8192][2048] f32
    const __bf16* __restrict__ Wt,    // [256][2048] bf16
    const float* __restrict__ bias,   // [256] f32
    __bf16* __restrict__ outb)        // [8192][256] bf16 normalized
{
    __shared__ __bf16 b_sh[2][DIM][FBK];  // 64 KB
    __shared__ __bf16 a_sh[2][FR][FBK];   // 8 KB
    __shared__ float  red[FR][4];
    __shared__ float  inv_sh[FR];

    const int tid  = threadIdx.x;
    const int wave = tid >> 6, lane = tid & 63;
    const int quad = lane >> 4, l15 = lane & 15;
    const int rowBase = blockIdx.x * FR;

    // A staging: thread -> (row, 8-float k-chunk)
    const int arow  = tid >> 3;            // 0..31
    const int ak    = (tid & 7) * 8;       // 0..56
    const int aslot = (tid & 7) ^ (arow & 7);
    // B staging: load i covers cols i*32+(tid>>3), granule tid&7
    const int bgs   = tid & 7;
    const int bcol0 = tid >> 3;

    f32x4 acc[2][4];
    const f32x4 zero = {0.f, 0.f, 0.f, 0.f};
#pragma unroll
    for (int m = 0; m < 2; m++)
#pragma unroll
        for (int n = 0; n < 4; n++) acc[m][n] = zero;

    f32x4 aLo0, aHi0, aLo1, aHi1;
    bf16x8v breg[8];

    const float* aRow = A + (size_t)(rowBase + arow) * EMB + ak;

    // ---- prologue: fill buffer 0, prefetch A(1) ----
    {
        aLo0 = *(const f32x4*)(aRow);
        aHi0 = *(const f32x4*)(aRow + 4);
#pragma unroll
        for (int i = 0; i < 8; i++)
            breg[i] = *(const bf16x8v*)(Wt + (size_t)(i * 32 + bcol0) * EMB + bgs * 8);
        bf16x8v av;
#pragma unroll
        for (int i = 0; i < 4; i++) { av[i] = (__bf16)aLo0[i]; av[4 + i] = (__bf16)aHi0[i]; }
        *(bf16x8v*)&a_sh[0][arow][aslot * 8] = av;
#pragma unroll
        for (int i = 0; i < 8; i++) {
            int col = i * 32 + bcol0;
            *(bf16x8v*)&b_sh[0][col][(bgs ^ (col & 7)) * 8] = breg[i];
        }
        aLo1 = *(const f32x4*)(aRow + FBK);
        aHi1 = *(const f32x4*)(aRow + FBK + 4);
    }
    __syncthreads();

    // ---- main loop ----
#pragma unroll 2
    for (int t = 0; t < FNIT; t++) {
        const int p = t & 1;
        // issue next-B loads (consumed at end of this iter)
        if (t + 1 < FNIT) {
            const __bf16* wb = Wt + (size_t)bcol0 * EMB + (t + 1) * FBK + bgs * 8;
#pragma unroll
            for (int i = 0; i < 8; i++)
                breg[i] = *(const bf16x8v*)(wb + (size_t)i * 32 * EMB);
        }
        // issue A loads two iters ahead
        if (t + 2 < FNIT) {
            const float* ap = aRow + (t + 2) * FBK;
            if (p == 0) { aLo0 = *(const f32x4*)ap; aHi0 = *(const f32x4*)(ap + 4); }
            else        { aLo1 = *(const f32x4*)ap; aHi1 = *(const f32x4*)(ap + 4); }
        }
        // compute current buffer
#pragma unroll
        for (int ks = 0; ks < 2; ks++) {
            bf16x8v af[2], bfv[4];
#pragma unroll
            for (int m = 0; m < 2; m++) {
                int row  = m * 16 + l15;
                int slot = (ks * 4 + quad) ^ (row & 7);
                af[m] = *(const bf16x8v*)&a_sh[p][row][slot * 8];
            }
#pragma unroll
            for (int n = 0; n < 4; n++) {
                int col  = wave * 64 + n * 16 + l15;
                int slot = (ks * 4 + quad) ^ (col & 7);
                bfv[n] = *(const bf16x8v*)&b_sh[p][col][slot * 8];
            }
#pragma unroll
            for (int m = 0; m < 2; m++)
#pragma unroll
                for (int n = 0; n < 4; n++)
                    acc[m][n] = __builtin_amdgcn_mfma_f32_16x16x32_bf16(af[m], bfv[n], acc[m][n], 0, 0, 0);
        }
        // write next buffer (A regs loaded 2 iters ago: no wait; B: counted vmcnt)
        if (t + 1 < FNIT) {
            bf16x8v av;
            if (p == 0) {
#pragma unroll
                for (int i = 0; i < 4; i++) { av[i] = (__bf16)aLo1[i]; av[4 + i] = (__bf16)aHi1[i]; }
            } else {
#pragma unroll
                for (int i = 0; i < 4; i++) { av[i] = (__bf16)aLo0[i]; av[4 + i] = (__bf16)aHi0[i]; }
            }
            *(bf16x8v*)&a_sh[p ^ 1][arow][aslot * 8] = av;
#pragma unroll
            for (int i = 0; i < 8; i++) {
                int col = i * 32 + bcol0;
                *(bf16x8v*)&b_sh[p ^ 1][col][(bgs ^ (col & 7)) * 8] = breg[i];
            }
        }
        __syncthreads();
    }

    // ---- epilogue: bias + row L2-norm + bf16 store ----
    float bv[4];
#pragma unroll
    for (int n = 0; n < 4; n++) bv[n] = bias[wave * 64 + n * 16 + l15];

    float ss[2][4];
#pragma unroll
    for (int m = 0; m < 2; m++)
#pragma unroll
        for (int r = 0; r < 4; r++) {
            float s = 0.f;
#pragma unroll
            for (int n = 0; n < 4; n++) {
                float v = acc[m][n][r] + bv[n];
                s += v * v;
            }
            ss[m][r] = s;
        }
#pragma unroll
    for (int off = 1; off < 16; off <<= 1)
#pragma unroll
        for (int m = 0; m < 2; m++)
#pragma unroll
            for (int r = 0; r < 4; r++) ss[m][r] += __shfl_xor(ss[m][r], off, 64);
    if (l15 == 0) {
#pragma unroll
        for (int m = 0; m < 2; m++)
#pragma unroll
            for (int r = 0; r < 4; r++) red[m * 16 + quad * 4 + r][wave] = ss[m][r];
    }
    __syncthreads();
    if (tid < FR) {
        float s = red[tid][0] + red[tid][1] + red[tid][2] + red[tid][3];
        inv_sh[tid] = 1.f / fmaxf(sqrtf(s), 1e-12f);
    }
    __syncthreads();
#pragma unroll
    for (int m = 0; m < 2; m++)
#pragma unroll
        for (int r = 0; r < 4; r++) {
            int row  = m * 16 + quad * 4 + r;
            float iv = inv_sh[row];
#pragma unroll
            for (int n = 0; n < 4; n++) {
                float v = acc[m][n][r] + bv[n];
                outb[(size_t)(rowBase + row) * DIM + wave * 64 + n * 16 + l15] = (__bf16)(v * iv);
            }
        }
}

// ---------- K2: sim = X@X^T. BK=64 streaming (32 KB LDS -> 3+ blocks/CU),
//              XOR-swizzled staging, shuffle-free unique-writer LDS epilogue, upper-tri grid ----------
#define TILE 128
#define NTILE (NROWS / TILE)              // 64
#define NBLK  (NTILE * (NTILE + 1) / 2)   // 2080

__global__ __launch_bounds__(256, 3) void sim_kernel(
    const __bf16* __restrict__ X,
    float* __restrict__ total,
    float* __restrict__ posv)
{
    __shared__ __align__(16) char smem[32768];
    __bf16* a_base = (__bf16*)smem;            // [2][128][32]
    __bf16* b_base = (__bf16*)(smem + 16384);  // [2][128][32]
    float*  rs     = (float*)smem;             // [128][2][16] = 16 KB
    float*  cs     = (float*)(smem + 16384);   // [128][2][4]  = 4 KB

    const int t = blockIdx.x;
    int bx = (int)((129.0 - sqrt(16641.0 - 8.0 * (double)t)) * 0.5);
    while (64 * (bx + 1) - ((bx + 1) * bx) / 2 <= t) bx++;
    while (64 * bx - (bx * (bx - 1)) / 2 > t) bx--;
    const int by = bx + (t - (64 * bx - (bx * (bx - 1)) / 2));
    const bool diag = (bx == by);

    const int tid  = threadIdx.x;
    const int wave = tid >> 6, lane = tid & 63;
    const int quad = lane >> 4, l15 = lane & 15;
    const int rowBase = bx * TILE;
    const int colBase = by * TILE;
    const int waveRow = (wave >> 1) * 64;
    const int waveCol = (wave & 1) * 64;

    f32x4 acc[4][4];
    const f32x4 zero = {0.f, 0.f, 0.f, 0.f};
#pragma unroll
    for (int m = 0; m < 4; m++)
#pragma unroll
        for (int n = 0; n < 4; n++) acc[m][n] = zero;

    const int r16 = lane >> 2;
    const int b4  = lane & 3;
    const int sw  = (r16 >> 1) & 3;   // stage-side swizzle
    const int sr  = (l15 >> 1) & 3;   // read-side swizzle

    for (int k0 = 0; k0 < DIM; k0 += 64) {
        __syncthreads();
#pragma unroll
        for (int c = 0; c < 2; c++) {
#pragma unroll
            for (int j = 0; j < 2; j++) {
                int rg = wave * 2 + j;   // row-group 0..7
                const __bf16* asrc = X + (size_t)(rowBase + rg * 16 + r16) * DIM + k0 + c * 32 + (b4 ^ sw) * 8;
                const __bf16* bsrc = X + (size_t)(colBase + rg * 16 + r16) * DIM + k0 + c * 32 + (b4 ^ sw) * 8;
                gld_lds16(asrc, a_base + (c * TILE + rg * 16) * 32);
                gld_lds16(bsrc, b_base + (c * TILE + rg * 16) * 32);
            }
        }
        __syncthreads();
#pragma unroll
        for (int ks = 0; ks < 2; ks++) {
            bf16x8v af[4], bfv[4];
#pragma unroll
            for (int m = 0; m < 4; m++)
                af[m] = *(const bf16x8v*)(a_base + (ks * TILE + waveRow + m * 16 + l15) * 32 + (quad ^ sr) * 8);
#pragma unroll
            for (int n = 0; n < 4; n++)
                bfv[n] = *(const bf16x8v*)(b_base + (ks * TILE + waveCol + n * 16 + l15) * 32 + (quad ^ sr) * 8);
#pragma unroll
            for (int m = 0; m < 4; m++)
#pragma unroll
                for (int n = 0; n < 4; n++)
                    acc[m][n] = __builtin_amdgcn_mfma_f32_16x16x32_bf16(af[m], bfv[n], acc[m][n], 0, 0, 0);
        }
    }

    float es[4][4];
    float ecol[4];
#pragma unroll
    for (int n = 0; n < 4; n++) ecol[n] = 0.f;
#pragma unroll
    for (int m = 0; m < 4; m++) {
#pragma unroll
        for (int r = 0; r < 4; r++) {
            int grow = rowBase + waveRow + m * 16 + quad * 4 + r;
            float e_acc = 0.f;
#pragma unroll
            for (int n = 0; n < 4; n++) {
                int gcol = colBase + waveCol + n * 16 + l15;
                float s = acc[m][n][r];
                if (gcol - grow == HALF) { posv[grow] = s; posv[gcol] = s; }
                float e = (gcol == grow) ? 0.f : __expf(s * INV_T);
                e_acc += e;
                ecol[n] += e;
            }
            es[m][r] = e_acc;
        }
    }

    __syncthreads();
    const int wc = wave & 1;
    const int wr = wave >> 1;
#pragma unroll
    for (int m = 0; m < 4; m++)
#pragma unroll
        for (int r = 0; r < 4; r++) {
            int lrow = waveRow + m * 16 + quad * 4 + r;
            rs[(lrow * 2 + wc) * 16 + l15] = es[m][r];
        }
    if (!diag) {
#pragma unroll
        for (int n = 0; n < 4; n++) {
            int lcol = waveCol + n * 16 + l15;
            cs[(lcol * 2 + wr) * 4 + quad] = ecol[n];
        }
    }
    __syncthreads();

    if (tid < TILE) {
        float rsum = 0.f;
#pragma unroll
        for (int i = 0; i < 32; i++) rsum += rs[tid * 32 + i];
        atomicAdd(&total[rowBase + tid], rsum);
        if (!diag) {
            float csum = 0.f;
#pragma unroll
            for (int i = 0; i < 8; i++) csum += cs[tid * 8 + i];
            atomicAdd(&total[colBase + tid], csum);
        }
    }
}

// ---------- K3: loss ----------
__global__ __launch_bounds__(256) void loss_kernel(
    const float* __restrict__ total, const float* __restrict__ posv,
    float* __restrict__ out)
{
    __shared__ float red[4];
    const int tid = threadIdx.x;
    const int i = blockIdx.x * 256 + tid;
    float s = posv[i] * INV_T - __logf(total[i]);
#pragma unroll
    for (int off = 1; off < 64; off <<= 1) s += __shfl_xor(s, off, 64);
    if ((tid & 63) == 0) red[tid >> 6] = s;
    __syncthreads();
    if (tid == 0) {
        float v = red[0] + red[1] + red[2] + red[3];
        atomicAdd(out, -v / (float)NROWS);
    }
}

extern "C" void kernel_launch(void* const* d_in, const int* in_sizes, int n_in,
                              void* d_out, int out_size, void* d_ws, size_t ws_size,
                              hipStream_t stream) {
    const float* emb  = (const float*)d_in[0];
    const float* W    = (const float*)d_in[1];
    const float* bias = (const float*)d_in[2];
    float* out = (float*)d_out;

    char* ws = (char*)d_ws;
    __bf16* outb  = (__bf16*)ws;                          // 4 MB
    __bf16* Wt    = (__bf16*)(ws + (4u << 20));           // 1 MB
    float*  total = (float*)(ws + (5u << 20));            // 32 KB
    float*  posv  = (float*)(ws + (5u << 20) + (32u << 10));

    hipMemsetAsync(total, 0, NROWS * sizeof(float), stream);
    hipMemsetAsync(out, 0, sizeof(float), stream);

    wt_kernel<<<dim3(DIM / 64, EMB / 64), 256, 0, stream>>>(W, Wt);
    gemm_norm_fused<<<dim3(NROWS / FR), 256, 0, stream>>>(emb, Wt, bias, outb);
    sim_kernel<<<dim3(NBLK), 256, 0, stream>>>(outb, total, posv);
    loss_kernel<<<dim3(NROWS / 256), 256, 0, stream>>>(total, posv, out);
}